// Round 4
// baseline (183.359 us; speedup 1.0000x reference)
//
#include <hip/hip_runtime.h>

#define IMG_W 1024
#define IMG_H 1024
#define NFRAMES 32
#define CROP 4
#define RPB 16   // output rows per block strip

__device__ __forceinline__ float4 ldg4(const float* p) {
    return *reinterpret_cast<const float4*>(p);
}

__global__ __launch_bounds__(256, 4) void gimbaless_sums(
    const float* __restrict__ A, const float* __restrict__ B,
    const float* __restrict__ lp9, double* __restrict__ sums)
{
    const int tid = threadIdx.x;
    const int v = blockIdx.x;   // vertical strip
    const int t = blockIdx.y;   // frame
    const size_t frame_off = (size_t)t * (IMG_W * IMG_H);
    const float* a = A + frame_off;
    const float* b = B + frame_off;

    // filter is symmetric (binomial): need taps 0..4 only
    const float lp0 = lp9[0], lp1 = lp9[1], lp2 = lp9[2], lp3 = lp9[3], lp4 = lp9[4];

    float s0=0.f,s1=0.f,s2=0.f,s3=0.f,s4=0.f,s5=0.f,s6=0.f,s7=0.f,s8=0.f;

    const int r0   = CROP + v * RPB;
    const int rend = min(r0 + RPB, IMG_H - CROP);

    if ((unsigned)(tid - 1) < 254u) {
        const int w0 = 4 * tid;                 // columns w0..w0+3
        const float x0 = (float)w0 - 511.5f;

        float d[9][4];    // dif rows h-4 .. h+4
        float av[6][4];   // avg rows h-1 .. h+4 (av[0]=h-1 ... av[2]=h+1)

        // ---- prologue: narrow rows r0-4 .. r0+4 ----
#pragma unroll
        for (int k = 0; k < 9; ++k) {
            const int r = r0 - 4 + k;
            float4 va = ldg4(a + (size_t)r * IMG_W + w0);
            float4 vb = ldg4(b + (size_t)r * IMG_W + w0);
            d[k][0] = va.x - vb.x; d[k][1] = va.y - vb.y;
            d[k][2] = va.z - vb.z; d[k][3] = va.w - vb.w;
            if (k >= 3) {
                av[k-3][0] = (va.x + vb.x) * 0.5f;
                av[k-3][1] = (va.y + vb.y) * 0.5f;
                av[k-3][2] = (va.z + vb.z) * 0.5f;
                av[k-3][3] = (va.w + vb.w) * 0.5f;
            }
        }
        // ---- prologue: side halos for row r0 ----
        float dl[4], dr[4], avl, avr;
        {
            float4 la = ldg4(a + (size_t)r0 * IMG_W + w0 - 4);
            float4 lb = ldg4(b + (size_t)r0 * IMG_W + w0 - 4);
            float4 ra = ldg4(a + (size_t)r0 * IMG_W + w0 + 4);
            float4 rb = ldg4(b + (size_t)r0 * IMG_W + w0 + 4);
            dl[0]=la.x-lb.x; dl[1]=la.y-lb.y; dl[2]=la.z-lb.z; dl[3]=la.w-lb.w;
            dr[0]=ra.x-rb.x; dr[1]=ra.y-rb.y; dr[2]=ra.z-rb.z; dr[3]=ra.w-rb.w;
            avl = (la.w + lb.w) * 0.5f;
            avr = (ra.x + rb.x) * 0.5f;
        }

#pragma unroll 1
        for (int h = r0; h < rend; ++h) {
            // ---- issue ALL loads for iteration h+1 up front ----
            const int hp = min(h + 5, IMG_H - 1);   // next narrow row
            const int hs = h + 1;                   // next side row (<=1020, in bounds)
            float4 pa = ldg4(a + (size_t)hp * IMG_W + w0);
            float4 pb = ldg4(b + (size_t)hp * IMG_W + w0);
            float4 la = ldg4(a + (size_t)hs * IMG_W + w0 - 4);
            float4 lb = ldg4(b + (size_t)hs * IMG_W + w0 - 4);
            float4 ra = ldg4(a + (size_t)hs * IMG_W + w0 + 4);
            float4 rb = ldg4(b + (size_t)hs * IMG_W + w0 + 4);

            // ---- compute row h from registers (overlaps the loads above) ----
            float dc[12];
            dc[0]=dl[0]; dc[1]=dl[1]; dc[2]=dl[2]; dc[3]=dl[3];
            dc[4]=d[4][0]; dc[5]=d[4][1]; dc[6]=d[4][2]; dc[7]=d[4][3];
            dc[8]=dr[0]; dc[9]=dr[1]; dc[10]=dr[2]; dc[11]=dr[3];
            float avc[6];
            avc[0]=avl;
            avc[1]=av[1][0]; avc[2]=av[1][1]; avc[3]=av[1][2]; avc[4]=av[1][3];
            avc[5]=avr;

            const float y = (float)h - 511.5f;
#pragma unroll
            for (int j = 0; j < 4; ++j) {
                const float px = (avc[j] - avc[j + 2]) * 0.5f;
                const float py = (av[0][j] - av[2][j]) * 0.5f;
                // symmetric 9-tap: lp[k] == lp[8-k]
                float ax = lp4 * dc[j + 4];
                ax = fmaf(lp0, dc[j] + dc[j + 8], ax);
                ax = fmaf(lp1, dc[j + 1] + dc[j + 7], ax);
                ax = fmaf(lp2, dc[j + 2] + dc[j + 6], ax);
                ax = fmaf(lp3, dc[j + 3] + dc[j + 5], ax);
                float ay = lp4 * d[4][j];
                ay = fmaf(lp0, d[0][j] + d[8][j], ay);
                ay = fmaf(lp1, d[1][j] + d[7][j], ay);
                ay = fmaf(lp2, d[2][j] + d[6][j], ay);
                ay = fmaf(lp3, d[3][j] + d[5][j], ay);

                const float x = x0 + (float)j;
                const float mom = px * y - py * x;
                s0 = fmaf(px, px, s0);
                s1 = fmaf(px, py, s1);
                s2 = fmaf(px, mom, s2);
                s3 = fmaf(py, py, s3);
                s4 = fmaf(py, mom, s4);
                s5 = fmaf(mom, mom, s5);
                const float tx = ax * px;
                const float ty = ay * py;
                s6 += tx;
                s7 += ty;
                s8 += tx * y - ty * x;
            }

            // ---- shift window, consume prefetched loads (single wait point) ----
#pragma unroll
            for (int k = 0; k < 8; ++k) {
                d[k][0] = d[k+1][0]; d[k][1] = d[k+1][1];
                d[k][2] = d[k+1][2]; d[k][3] = d[k+1][3];
            }
#pragma unroll
            for (int k = 0; k < 5; ++k) {
                av[k][0] = av[k+1][0]; av[k][1] = av[k+1][1];
                av[k][2] = av[k+1][2]; av[k][3] = av[k+1][3];
            }
            d[8][0] = pa.x - pb.x; d[8][1] = pa.y - pb.y;
            d[8][2] = pa.z - pb.z; d[8][3] = pa.w - pb.w;
            av[5][0] = (pa.x + pb.x) * 0.5f;
            av[5][1] = (pa.y + pb.y) * 0.5f;
            av[5][2] = (pa.z + pb.z) * 0.5f;
            av[5][3] = (pa.w + pb.w) * 0.5f;
            dl[0]=la.x-lb.x; dl[1]=la.y-lb.y; dl[2]=la.z-lb.z; dl[3]=la.w-lb.w;
            dr[0]=ra.x-rb.x; dr[1]=ra.y-rb.y; dr[2]=ra.z-rb.z; dr[3]=ra.w-rb.w;
            avl = (la.w + lb.w) * 0.5f;
            avr = (ra.x + rb.x) * 0.5f;
        }
    }

    // ---- reduction: f64 wave shuffle -> LDS -> global atomic ----
    double ds[9];
    ds[0]=s0; ds[1]=s1; ds[2]=s2; ds[3]=s3; ds[4]=s4;
    ds[5]=s5; ds[6]=s6; ds[7]=s7; ds[8]=s8;
#pragma unroll
    for (int k = 0; k < 9; ++k) {
        double x = ds[k];
        for (int off = 32; off > 0; off >>= 1)
            x += __shfl_down(x, off);
        ds[k] = x;
    }
    __shared__ double red[4][9];
    const int wave = tid >> 6, lane = tid & 63;
    if (lane == 0) {
#pragma unroll
        for (int k = 0; k < 9; ++k) red[wave][k] = ds[k];
    }
    __syncthreads();
    if (tid < 9) {
        double tot = red[0][tid] + red[1][tid] + red[2][tid] + red[3][tid];
        atomicAdd(&sums[(size_t)t * 9 + tid], tot);
    }
}

__global__ void gimbaless_solve(const double* __restrict__ sums, float* __restrict__ out)
{
    const int t = threadIdx.x;
    if (t < NFRAMES) {
        const double* s = sums + (size_t)t * 9;
        const double m00=s[0], m01=s[1], m02=s[2], m11=s[3], m12=s[4], m22=s[5];
        const double b0=s[6], b1=s[7], b2=s[8];
        const double c00 = m11*m22 - m12*m12;
        const double c01 = m02*m12 - m01*m22;
        const double c02 = m01*m12 - m02*m11;
        const double c11 = m00*m22 - m02*m02;
        const double c12 = m01*m02 - m00*m12;
        const double c22 = m00*m11 - m01*m01;
        const double det = m00*c00 + m01*c01 + m02*c02;
        const double inv = 1.0 / det;
        out[t]              = (float)((c00*b0 + c01*b1 + c02*b2) * inv);
        out[NFRAMES + t]    = (float)((c01*b0 + c11*b1 + c12*b2) * inv);
        out[2*NFRAMES + t]  = (float)((c02*b0 + c12*b1 + c22*b2) * inv);
    }
}

extern "C" void kernel_launch(void* const* d_in, const int* in_sizes, int n_in,
                              void* d_out, int out_size, void* d_ws, size_t ws_size,
                              hipStream_t stream) {
    const float* A  = (const float*)d_in[0];
    const float* B  = (const float*)d_in[1];
    const float* lp = (const float*)d_in[2];
    double* sums = (double*)d_ws;

    hipMemsetAsync(d_ws, 0, NFRAMES * 9 * sizeof(double), stream);

    dim3 grid((IMG_H - 2*CROP + RPB - 1) / RPB, NFRAMES);  // (64, 32)
    gimbaless_sums<<<grid, 256, 0, stream>>>(A, B, lp, sums);
    gimbaless_solve<<<1, 64, 0, stream>>>(sums, (float*)d_out);
}

// Round 5
// 102.731 us; speedup vs baseline: 1.7849x; 1.7849x over previous
//
#include <hip/hip_runtime.h>

#define IMG_W 1024
#define IMG_H 1024
#define NFRAMES 32
#define CROP 4
#define RPB 16   // output rows per block strip

__device__ __forceinline__ float4 ldg4(const float* p) {
    return *reinterpret_cast<const float4*>(p);
}

__global__ __launch_bounds__(256) void gimbaless_sums(
    const float* __restrict__ A, const float* __restrict__ B,
    const float* __restrict__ lp9, double* __restrict__ sums)
{
    const int tid = threadIdx.x;
    const int v = blockIdx.x;   // vertical strip
    const int t = blockIdx.y;   // frame
    const size_t frame_off = (size_t)t * (IMG_W * IMG_H);
    const float* a = A + frame_off;
    const float* b = B + frame_off;

    // filter is symmetric (binomial): need taps 0..4 only
    const float lp0 = lp9[0], lp1 = lp9[1], lp2 = lp9[2], lp3 = lp9[3], lp4 = lp9[4];

    float s0=0.f,s1=0.f,s2=0.f,s3=0.f,s4=0.f,s5=0.f,s6=0.f,s7=0.f,s8=0.f;

    const int r0   = CROP + v * RPB;
    const int rend = min(r0 + RPB, IMG_H - CROP);

    if ((unsigned)(tid - 1) < 254u) {
        const int w0 = 4 * tid;                 // columns w0..w0+3
        const float x0 = (float)w0 - 511.5f;

        float d[9][4];    // dif rows h-4 .. h+4
        float av[6][4];   // avg rows h-1 .. h+4

        // ---- prologue: narrow rows r0-4 .. r0+4 ----
#pragma unroll
        for (int k = 0; k < 9; ++k) {
            const int r = r0 - 4 + k;
            float4 va = ldg4(a + (size_t)r * IMG_W + w0);
            float4 vb = ldg4(b + (size_t)r * IMG_W + w0);
            d[k][0] = va.x - vb.x; d[k][1] = va.y - vb.y;
            d[k][2] = va.z - vb.z; d[k][3] = va.w - vb.w;
            if (k >= 3) {
                av[k-3][0] = (va.x + vb.x) * 0.5f;
                av[k-3][1] = (va.y + vb.y) * 0.5f;
                av[k-3][2] = (va.z + vb.z) * 0.5f;
                av[k-3][3] = (va.w + vb.w) * 0.5f;
            }
        }
        // ---- prologue: side halos for row r0 ----
        float dl[4], dr[4], avl, avr;
        {
            float4 la = ldg4(a + (size_t)r0 * IMG_W + w0 - 4);
            float4 lb = ldg4(b + (size_t)r0 * IMG_W + w0 - 4);
            float4 ra = ldg4(a + (size_t)r0 * IMG_W + w0 + 4);
            float4 rb = ldg4(b + (size_t)r0 * IMG_W + w0 + 4);
            dl[0]=la.x-lb.x; dl[1]=la.y-lb.y; dl[2]=la.z-lb.z; dl[3]=la.w-lb.w;
            dr[0]=ra.x-rb.x; dr[1]=ra.y-rb.y; dr[2]=ra.z-rb.z; dr[3]=ra.w-rb.w;
            avl = (la.w + lb.w) * 0.5f;
            avr = (ra.x + rb.x) * 0.5f;
        }

#pragma unroll 1
        for (int h = r0; h < rend; ++h) {
            // ---- issue ALL loads for iteration h+1 up front ----
            const int hp = min(h + 5, IMG_H - 1);   // next narrow row
            const int hs = h + 1;                   // next side row (<=1020, in bounds)
            float4 pa = ldg4(a + (size_t)hp * IMG_W + w0);
            float4 pb = ldg4(b + (size_t)hp * IMG_W + w0);
            float4 la = ldg4(a + (size_t)hs * IMG_W + w0 - 4);
            float4 lb = ldg4(b + (size_t)hs * IMG_W + w0 - 4);
            float4 ra = ldg4(a + (size_t)hs * IMG_W + w0 + 4);
            float4 rb = ldg4(b + (size_t)hs * IMG_W + w0 + 4);

            // ---- compute row h from registers (overlaps the loads above) ----
            float dc[12];
            dc[0]=dl[0]; dc[1]=dl[1]; dc[2]=dl[2]; dc[3]=dl[3];
            dc[4]=d[4][0]; dc[5]=d[4][1]; dc[6]=d[4][2]; dc[7]=d[4][3];
            dc[8]=dr[0]; dc[9]=dr[1]; dc[10]=dr[2]; dc[11]=dr[3];
            float avc[6];
            avc[0]=avl;
            avc[1]=av[1][0]; avc[2]=av[1][1]; avc[3]=av[1][2]; avc[4]=av[1][3];
            avc[5]=avr;

            const float y = (float)h - 511.5f;
#pragma unroll
            for (int j = 0; j < 4; ++j) {
                const float px = (avc[j] - avc[j + 2]) * 0.5f;
                const float py = (av[0][j] - av[2][j]) * 0.5f;
                // symmetric 9-tap: lp[k] == lp[8-k]
                float ax = lp4 * dc[j + 4];
                ax = fmaf(lp0, dc[j] + dc[j + 8], ax);
                ax = fmaf(lp1, dc[j + 1] + dc[j + 7], ax);
                ax = fmaf(lp2, dc[j + 2] + dc[j + 6], ax);
                ax = fmaf(lp3, dc[j + 3] + dc[j + 5], ax);
                float ay = lp4 * d[4][j];
                ay = fmaf(lp0, d[0][j] + d[8][j], ay);
                ay = fmaf(lp1, d[1][j] + d[7][j], ay);
                ay = fmaf(lp2, d[2][j] + d[6][j], ay);
                ay = fmaf(lp3, d[3][j] + d[5][j], ay);

                const float x = x0 + (float)j;
                const float mom = px * y - py * x;
                s0 = fmaf(px, px, s0);
                s1 = fmaf(px, py, s1);
                s2 = fmaf(px, mom, s2);
                s3 = fmaf(py, py, s3);
                s4 = fmaf(py, mom, s4);
                s5 = fmaf(mom, mom, s5);
                const float tx = ax * px;
                const float ty = ay * py;
                s6 += tx;
                s7 += ty;
                s8 += tx * y - ty * x;
            }

            // ---- shift window, consume prefetched loads (single wait point) ----
#pragma unroll
            for (int k = 0; k < 8; ++k) {
                d[k][0] = d[k+1][0]; d[k][1] = d[k+1][1];
                d[k][2] = d[k+1][2]; d[k][3] = d[k+1][3];
            }
#pragma unroll
            for (int k = 0; k < 5; ++k) {
                av[k][0] = av[k+1][0]; av[k][1] = av[k+1][1];
                av[k][2] = av[k+1][2]; av[k][3] = av[k+1][3];
            }
            d[8][0] = pa.x - pb.x; d[8][1] = pa.y - pb.y;
            d[8][2] = pa.z - pb.z; d[8][3] = pa.w - pb.w;
            av[5][0] = (pa.x + pb.x) * 0.5f;
            av[5][1] = (pa.y + pb.y) * 0.5f;
            av[5][2] = (pa.z + pb.z) * 0.5f;
            av[5][3] = (pa.w + pb.w) * 0.5f;
            dl[0]=la.x-lb.x; dl[1]=la.y-lb.y; dl[2]=la.z-lb.z; dl[3]=la.w-lb.w;
            dr[0]=ra.x-rb.x; dr[1]=ra.y-rb.y; dr[2]=ra.z-rb.z; dr[3]=ra.w-rb.w;
            avl = (la.w + lb.w) * 0.5f;
            avr = (ra.x + rb.x) * 0.5f;
        }
    }

    // ---- reduction: f64 wave shuffle -> LDS -> global atomic ----
    double ds[9];
    ds[0]=s0; ds[1]=s1; ds[2]=s2; ds[3]=s3; ds[4]=s4;
    ds[5]=s5; ds[6]=s6; ds[7]=s7; ds[8]=s8;
#pragma unroll
    for (int k = 0; k < 9; ++k) {
        double x = ds[k];
        for (int off = 32; off > 0; off >>= 1)
            x += __shfl_down(x, off);
        ds[k] = x;
    }
    __shared__ double red[4][9];
    const int wave = tid >> 6, lane = tid & 63;
    if (lane == 0) {
#pragma unroll
        for (int k = 0; k < 9; ++k) red[wave][k] = ds[k];
    }
    __syncthreads();
    if (tid < 9) {
        double tot = red[0][tid] + red[1][tid] + red[2][tid] + red[3][tid];
        atomicAdd(&sums[(size_t)t * 9 + tid], tot);
    }
}

__global__ void gimbaless_solve(const double* __restrict__ sums, float* __restrict__ out)
{
    const int t = threadIdx.x;
    if (t < NFRAMES) {
        const double* s = sums + (size_t)t * 9;
        const double m00=s[0], m01=s[1], m02=s[2], m11=s[3], m12=s[4], m22=s[5];
        const double b0=s[6], b1=s[7], b2=s[8];
        const double c00 = m11*m22 - m12*m12;
        const double c01 = m02*m12 - m01*m22;
        const double c02 = m01*m12 - m02*m11;
        const double c11 = m00*m22 - m02*m02;
        const double c12 = m01*m02 - m00*m12;
        const double c22 = m00*m11 - m01*m01;
        const double det = m00*c00 + m01*c01 + m02*c02;
        const double inv = 1.0 / det;
        out[t]              = (float)((c00*b0 + c01*b1 + c02*b2) * inv);
        out[NFRAMES + t]    = (float)((c01*b0 + c11*b1 + c12*b2) * inv);
        out[2*NFRAMES + t]  = (float)((c02*b0 + c12*b1 + c22*b2) * inv);
    }
}

extern "C" void kernel_launch(void* const* d_in, const int* in_sizes, int n_in,
                              void* d_out, int out_size, void* d_ws, size_t ws_size,
                              hipStream_t stream) {
    const float* A  = (const float*)d_in[0];
    const float* B  = (const float*)d_in[1];
    const float* lp = (const float*)d_in[2];
    double* sums = (double*)d_ws;

    hipMemsetAsync(d_ws, 0, NFRAMES * 9 * sizeof(double), stream);

    dim3 grid((IMG_H - 2*CROP + RPB - 1) / RPB, NFRAMES);  // (64, 32)
    gimbaless_sums<<<grid, 256, 0, stream>>>(A, B, lp, sums);
    gimbaless_solve<<<1, 64, 0, stream>>>(sums, (float*)d_out);
}

// Round 7
// 89.342 us; speedup vs baseline: 2.0523x; 1.1499x over previous
//
#include <hip/hip_runtime.h>

#define IMG_W 1024
#define IMG_H 1024
#define NFRAMES 32
#define CROP 4
#define RPB 44          // output rows per band: ceil(1016/44)=24 bands
#define RING 6          // LDS ring slots (rows) per tensor
#define ROWB 4096       // bytes per staged row (1024 f32)
#define ABYTES (RING*ROWB)   // 24576 per tensor; total 48 KiB -> 3 blocks/CU

__device__ __forceinline__ void gl_lds16(const float* g, void* l) {
    __builtin_amdgcn_global_load_lds(
        (const __attribute__((address_space(1))) void*)g,
        (__attribute__((address_space(3))) void*)l,
        16, 0, 0);
}

__global__ __launch_bounds__(256) void gimbaless_sums(
    const float* __restrict__ A, const float* __restrict__ B,
    const float* __restrict__ lp9, double* __restrict__ sums)
{
    __shared__ __align__(16) unsigned char smem[2 * ABYTES];

    const int tid  = threadIdx.x;
    const int band = blockIdx.x;
    const int t    = blockIdx.y;
    const float* a = A + (size_t)t * (IMG_W * IMG_H);
    const float* b = B + (size_t)t * (IMG_W * IMG_H);

    const float lp0 = lp9[0], lp1 = lp9[1], lp2 = lp9[2], lp3 = lp9[3], lp4 = lp9[4];

    const int r0   = CROP + band * RPB;
    const int rend = min(r0 + RPB, IMG_H - CROP);

    const int t16 = tid * 16;            // this thread's byte offset within a row
    const int wb  = (tid >> 6) * 1024;   // wave-uniform LDS offset (1 KiB per wave)

    // stage row r of both tensors into ring slot r%RING (async DMA, 2 instrs/wave)
    auto stage = [&](int r) {
        const int slot = r % RING;
        gl_lds16(a + (size_t)r * IMG_W + tid * 4, smem + slot * ROWB + wb);
        gl_lds16(b + (size_t)r * IMG_W + tid * 4, smem + ABYTES + slot * ROWB + wb);
    };
    auto rdA = [&](int slot, int off) -> float4 {
        return *(const float4*)(smem + slot * ROWB + off);
    };
    auto rdB = [&](int slot, int off) -> float4 {
        return *(const float4*)(smem + ABYTES + slot * ROWB + off);
    };

    float s0=0.f,s1=0.f,s2=0.f,s3=0.f,s4=0.f,s5=0.f,s6=0.f,s7=0.f,s8=0.f;
    float d[9][4];    // dif rows h-4..h+4
    float av[6][4];   // avg rows h-1..h+4
    const bool active = ((unsigned)(tid - 1) < 254u);
    const int w0 = 4 * tid;
    const float x0 = (float)w0 - 511.5f;

    // ---- Phase A: stage rows r0-4 .. r0+1 (6 rows fill the ring) ----
    for (int r = r0 - 4; r <= r0 + 1; ++r) stage(r);
    __syncthreads();

    // ---- Phase B: read rows r0-4..r0+1 into window ----
    if (active) {
#pragma unroll
        for (int k = 0; k < 6; ++k) {
            const int r = r0 - 4 + k;
            const int slot = r % RING;
            float4 va = rdA(slot, t16);
            float4 vb = rdB(slot, t16);
            d[k][0]=va.x-vb.x; d[k][1]=va.y-vb.y; d[k][2]=va.z-vb.z; d[k][3]=va.w-vb.w;
            if (k >= 3) {
                av[k-3][0]=(va.x+vb.x)*0.5f; av[k-3][1]=(va.y+vb.y)*0.5f;
                av[k-3][2]=(va.z+vb.z)*0.5f; av[k-3][3]=(va.w+vb.w)*0.5f;
            }
        }
    }
    __syncthreads();
    // ---- stage rows r0+2..r0+4 (recycle slots of r0-4..r0-2, already read) ----
    stage(r0 + 2); stage(r0 + 3); stage(r0 + 4);
    __syncthreads();
    // ---- Phase C: read rows r0+2, r0+3 into window ----
    if (active) {
#pragma unroll
        for (int k = 6; k < 8; ++k) {
            const int r = r0 - 4 + k;
            const int slot = r % RING;
            float4 va = rdA(slot, t16);
            float4 vb = rdB(slot, t16);
            d[k][0]=va.x-vb.x; d[k][1]=va.y-vb.y; d[k][2]=va.z-vb.z; d[k][3]=va.w-vb.w;
            av[k-3][0]=(va.x+vb.x)*0.5f; av[k-3][1]=(va.y+vb.y)*0.5f;
            av[k-3][2]=(va.z+vb.z)*0.5f; av[k-3][3]=(va.w+vb.w)*0.5f;
        }
    }

    // ---- main loop: one output row per iteration ----
#pragma unroll 1
    for (int h = r0; h < rend; ++h) {
        if (h + 5 <= rend + 3) stage(h + 5);   // async prefetch, slot of row h-1 (free)

        if (active) {
            const int slot4 = (h + 4) % RING;
            const int sloth = h % RING;
            float4 na = rdA(slot4, t16),      nb = rdB(slot4, t16);
            float4 la = rdA(sloth, t16 - 16), lb = rdB(sloth, t16 - 16);
            float4 ra = rdA(sloth, t16 + 16), rb = rdB(sloth, t16 + 16);

            d[8][0]=na.x-nb.x; d[8][1]=na.y-nb.y; d[8][2]=na.z-nb.z; d[8][3]=na.w-nb.w;
            av[5][0]=(na.x+nb.x)*0.5f; av[5][1]=(na.y+nb.y)*0.5f;
            av[5][2]=(na.z+nb.z)*0.5f; av[5][3]=(na.w+nb.w)*0.5f;

            float dc[12];
            dc[0]=la.x-lb.x; dc[1]=la.y-lb.y; dc[2]=la.z-lb.z; dc[3]=la.w-lb.w;
            dc[4]=d[4][0]; dc[5]=d[4][1]; dc[6]=d[4][2]; dc[7]=d[4][3];
            dc[8]=ra.x-rb.x; dc[9]=ra.y-rb.y; dc[10]=ra.z-rb.z; dc[11]=ra.w-rb.w;
            float avc[6];
            avc[0]=(la.w+lb.w)*0.5f;
            avc[1]=av[1][0]; avc[2]=av[1][1]; avc[3]=av[1][2]; avc[4]=av[1][3];
            avc[5]=(ra.x+rb.x)*0.5f;

            const float y = (float)h - 511.5f;
#pragma unroll
            for (int j = 0; j < 4; ++j) {
                const float px = (avc[j] - avc[j + 2]) * 0.5f;
                const float py = (av[0][j] - av[2][j]) * 0.5f;
                float ax = lp4 * dc[j + 4];
                ax = fmaf(lp0, dc[j] + dc[j + 8], ax);
                ax = fmaf(lp1, dc[j + 1] + dc[j + 7], ax);
                ax = fmaf(lp2, dc[j + 2] + dc[j + 6], ax);
                ax = fmaf(lp3, dc[j + 3] + dc[j + 5], ax);
                float ay = lp4 * d[4][j];
                ay = fmaf(lp0, d[0][j] + d[8][j], ay);
                ay = fmaf(lp1, d[1][j] + d[7][j], ay);
                ay = fmaf(lp2, d[2][j] + d[6][j], ay);
                ay = fmaf(lp3, d[3][j] + d[5][j], ay);

                const float x = x0 + (float)j;
                const float mom = px * y - py * x;
                s0 = fmaf(px, px, s0);
                s1 = fmaf(px, py, s1);
                s2 = fmaf(px, mom, s2);
                s3 = fmaf(py, py, s3);
                s4 = fmaf(py, mom, s4);
                s5 = fmaf(mom, mom, s5);
                const float tx = ax * px;
                const float ty = ay * py;
                s6 += tx;
                s7 += ty;
                s8 += tx * y - ty * x;
            }

#pragma unroll
            for (int k = 0; k < 8; ++k) {
                d[k][0]=d[k+1][0]; d[k][1]=d[k+1][1]; d[k][2]=d[k+1][2]; d[k][3]=d[k+1][3];
            }
#pragma unroll
            for (int k = 0; k < 5; ++k) {
                av[k][0]=av[k+1][0]; av[k][1]=av[k+1][1]; av[k][2]=av[k+1][2]; av[k][3]=av[k+1][3];
            }
        }
        __syncthreads();   // drains stage(h+5); protects ring-slot reuse
    }

    // ---- reduction: f64 wave shuffle -> LDS (aliased) -> global atomic ----
    double ds[9];
    ds[0]=s0; ds[1]=s1; ds[2]=s2; ds[3]=s3; ds[4]=s4;
    ds[5]=s5; ds[6]=s6; ds[7]=s7; ds[8]=s8;
#pragma unroll
    for (int k = 0; k < 9; ++k) {
        double x = ds[k];
        for (int off = 32; off > 0; off >>= 1)
            x += __shfl_down(x, off);
        ds[k] = x;
    }
    double (*red)[9] = (double(*)[9])smem;   // alias ring buffer (done with it)
    const int wave = tid >> 6, lane = tid & 63;
    if (lane == 0) {
#pragma unroll
        for (int k = 0; k < 9; ++k) red[wave][k] = ds[k];
    }
    __syncthreads();
    if (tid < 9) {
        double tot = red[0][tid] + red[1][tid] + red[2][tid] + red[3][tid];
        atomicAdd(&sums[(size_t)t * 9 + tid], tot);
    }
}

__global__ void gimbaless_solve(const double* __restrict__ sums, float* __restrict__ out)
{
    const int t = threadIdx.x;
    if (t < NFRAMES) {
        const double* s = sums + (size_t)t * 9;
        const double m00=s[0], m01=s[1], m02=s[2], m11=s[3], m12=s[4], m22=s[5];
        const double b0=s[6], b1=s[7], b2=s[8];
        const double c00 = m11*m22 - m12*m12;
        const double c01 = m02*m12 - m01*m22;
        const double c02 = m01*m12 - m02*m11;
        const double c11 = m00*m22 - m02*m02;
        const double c12 = m01*m02 - m00*m12;
        const double c22 = m00*m11 - m01*m01;
        const double det = m00*c00 + m01*c01 + m02*c02;
        const double inv = 1.0 / det;
        out[t]             = (float)((c00*b0 + c01*b1 + c02*b2) * inv);
        out[NFRAMES + t]   = (float)((c01*b0 + c11*b1 + c12*b2) * inv);
        out[2*NFRAMES + t] = (float)((c02*b0 + c12*b1 + c22*b2) * inv);
    }
}

extern "C" void kernel_launch(void* const* d_in, const int* in_sizes, int n_in,
                              void* d_out, int out_size, void* d_ws, size_t ws_size,
                              hipStream_t stream) {
    const float* A  = (const float*)d_in[0];
    const float* B  = (const float*)d_in[1];
    const float* lp = (const float*)d_in[2];
    double* sums = (double*)d_ws;

    hipMemsetAsync(d_ws, 0, NFRAMES * 9 * sizeof(double), stream);

    dim3 grid((IMG_H - 2*CROP + RPB - 1) / RPB, NFRAMES);  // (24, 32)
    gimbaless_sums<<<grid, 256, 0, stream>>>(A, B, lp, sums);
    gimbaless_solve<<<1, 64, 0, stream>>>(sums, (float*)d_out);
}